// Round 1
// baseline (93.261 us; speedup 1.0000x reference)
//
#include <hip/hip_runtime.h>

#define N_NODES 50000
#define N_EDGES 640000
#define D 128

// Kernel 1: one wave per node; s1[n] = X[n]·W1, s2[n] = X[n]·W2.
// Lane i loads X[n][2i..2i+1] as float2 -> 512B contiguous per wave (coalesced).
__global__ __launch_bounds__(256) void node_scores_kernel(
    const float* __restrict__ X,
    const float* __restrict__ W1,
    const float* __restrict__ W2,
    float* __restrict__ s1,
    float* __restrict__ s2,
    int n_nodes, int total_waves)
{
    const int lane = threadIdx.x & 63;
    const int wave = blockIdx.x * (blockDim.x >> 6) + (threadIdx.x >> 6);

    // W1/W2 fragments live in registers for the whole kernel.
    const float2 w1 = ((const float2*)W1)[lane];
    const float2 w2 = ((const float2*)W2)[lane];

    for (int n = wave; n < n_nodes; n += total_waves) {
        const float2 x = ((const float2*)(X + (size_t)n * D))[lane];
        float p1 = x.x * w1.x + x.y * w1.y;
        float p2 = x.x * w2.x + x.y * w2.y;
        // 64-lane butterfly reduction (wave = 64 on CDNA).
        #pragma unroll
        for (int off = 32; off > 0; off >>= 1) {
            p1 += __shfl_xor(p1, off, 64);
            p2 += __shfl_xor(p2, off, 64);
        }
        if (lane == 0) {
            s1[n] = p1;
            s2[n] = p2;
        }
    }
}

// Kernel 2: out[e] = s1[src[e]] + s2[dst[e]]; 4 edges per thread.
// src/dst index streams are coalesced int4 loads; s1/s2 are 200KB each
// (L2-resident); output is a coalesced float4 store.
__global__ __launch_bounds__(256) void edge_combine_kernel(
    const int* __restrict__ src,
    const int* __restrict__ dst,
    const float* __restrict__ s1,
    const float* __restrict__ s2,
    float* __restrict__ out,
    int n4)
{
    const int i = blockIdx.x * blockDim.x + threadIdx.x;
    if (i < n4) {
        const int4 s = ((const int4*)src)[i];
        const int4 d = ((const int4*)dst)[i];
        float4 o;
        o.x = s1[s.x] + s2[d.x];
        o.y = s1[s.y] + s2[d.y];
        o.z = s1[s.z] + s2[d.z];
        o.w = s1[s.w] + s2[d.w];
        ((float4*)out)[i] = o;
    }
}

extern "C" void kernel_launch(void* const* d_in, const int* in_sizes, int n_in,
                              void* d_out, int out_size, void* d_ws, size_t ws_size,
                              hipStream_t stream) {
    const float* X  = (const float*)d_in[0];   // [N_NODES, D]
    const int*   ei = (const int*)d_in[1];     // [2, N_EDGES] (int32 on device)
    const float* W1 = (const float*)d_in[2];   // [1, D]
    const float* W2 = (const float*)d_in[3];   // [1, D]
    float* out = (float*)d_out;                // [N_EDGES, 1]

    // Workspace: two per-node scalar tables (fully overwritten each call).
    float* s1 = (float*)d_ws;
    float* s2 = s1 + N_NODES;

    // Kernel 1: 512 blocks x 4 waves = 2048 waves; ~25 nodes/wave.
    const int blocks1 = 512;
    node_scores_kernel<<<blocks1, 256, 0, stream>>>(X, W1, W2, s1, s2,
                                                    N_NODES, blocks1 * 4);

    // Kernel 2: 160000 threads (4 edges each) -> 625 blocks of 256.
    const int n4 = N_EDGES / 4;
    edge_combine_kernel<<<(n4 + 255) / 256, 256, 0, stream>>>(
        ei, ei + N_EDGES, s1, s2, out, n4);
}

// Round 2
// 84.361 us; speedup vs baseline: 1.1055x; 1.1055x over previous
//
#include <hip/hip_runtime.h>

#define N_NODES 50000
#define N_EDGES 640000
#define D 128

// Kernel 1: 16 lanes per node (4 nodes per wave-iteration).
// Lane sl (0..15) loads X[n][sl*8 .. sl*8+7] as two float4 (32B/lane, 512B
// contiguous per node). Butterfly-reduce over 16 lanes: 4 steps x 2 dots.
__global__ __launch_bounds__(256) void node_scores_kernel(
    const float* __restrict__ X,
    const float* __restrict__ W1,
    const float* __restrict__ W2,
    float* __restrict__ s1,
    float* __restrict__ s2,
    int n_nodes, int total_groups)
{
    const int lane = threadIdx.x & 63;
    const int sl   = lane & 15;          // lane within 16-lane group
    const int sub  = lane >> 4;          // group within wave (0..3)
    const int wave = blockIdx.x * (blockDim.x >> 6) + (threadIdx.x >> 6);
    const int g    = wave * 4 + sub;     // global 16-lane group id

    // W fragments in registers for the whole kernel.
    const float4* W1v = (const float4*)W1;
    const float4* W2v = (const float4*)W2;
    const float4 w1a = W1v[sl * 2],     w1b = W1v[sl * 2 + 1];
    const float4 w2a = W2v[sl * 2],     w2b = W2v[sl * 2 + 1];

    for (int n = g; n < n_nodes; n += total_groups) {
        const float4* Xv = (const float4*)(X + (size_t)n * D);
        const float4 x0 = Xv[sl * 2];
        const float4 x1 = Xv[sl * 2 + 1];
        float p1 = x0.x * w1a.x + x0.y * w1a.y + x0.z * w1a.z + x0.w * w1a.w
                 + x1.x * w1b.x + x1.y * w1b.y + x1.z * w1b.z + x1.w * w1b.w;
        float p2 = x0.x * w2a.x + x0.y * w2a.y + x0.z * w2a.z + x0.w * w2a.w
                 + x1.x * w2b.x + x1.y * w2b.y + x1.z * w2b.z + x1.w * w2b.w;
        // Reduce across the 16-lane group (xor offsets < 16 stay in-group).
        #pragma unroll
        for (int off = 8; off > 0; off >>= 1) {
            p1 += __shfl_xor(p1, off, 64);
            p2 += __shfl_xor(p2, off, 64);
        }
        if (sl == 0) {
            s1[n] = p1;
            s2[n] = p2;
        }
    }
}

// Kernel 2: out[e] = s1[src[e]] + s2[dst[e]]; 8 edges per thread.
// Index streams: 2x int4 coalesced loads; gathers hit the 200KB L2-resident
// tables; output: 2x float4 coalesced stores.
__global__ __launch_bounds__(256) void edge_combine_kernel(
    const int* __restrict__ src,
    const int* __restrict__ dst,
    const float* __restrict__ s1,
    const float* __restrict__ s2,
    float* __restrict__ out,
    int n8)
{
    const int i = blockIdx.x * blockDim.x + threadIdx.x;
    if (i < n8) {
        const int4 sa = ((const int4*)src)[2 * i];
        const int4 sb = ((const int4*)src)[2 * i + 1];
        const int4 da = ((const int4*)dst)[2 * i];
        const int4 db = ((const int4*)dst)[2 * i + 1];
        float4 oa, ob;
        oa.x = s1[sa.x] + s2[da.x];
        oa.y = s1[sa.y] + s2[da.y];
        oa.z = s1[sa.z] + s2[da.z];
        oa.w = s1[sa.w] + s2[da.w];
        ob.x = s1[sb.x] + s2[db.x];
        ob.y = s1[sb.y] + s2[db.y];
        ob.z = s1[sb.z] + s2[db.z];
        ob.w = s1[sb.w] + s2[db.w];
        ((float4*)out)[2 * i]     = oa;
        ((float4*)out)[2 * i + 1] = ob;
    }
}

extern "C" void kernel_launch(void* const* d_in, const int* in_sizes, int n_in,
                              void* d_out, int out_size, void* d_ws, size_t ws_size,
                              hipStream_t stream) {
    const float* X  = (const float*)d_in[0];   // [N_NODES, D]
    const int*   ei = (const int*)d_in[1];     // [2, N_EDGES] (int32 on device)
    const float* W1 = (const float*)d_in[2];   // [1, D]
    const float* W2 = (const float*)d_in[3];   // [1, D]
    float* out = (float*)d_out;                // [N_EDGES, 1]

    // Workspace: two per-node scalar tables (fully overwritten each call).
    float* s1 = (float*)d_ws;
    float* s2 = s1 + N_NODES;

    // Kernel 1: 512 blocks x 4 waves x 4 groups = 8192 groups; ~6 nodes/group.
    const int blocks1 = 512;
    node_scores_kernel<<<blocks1, 256, 0, stream>>>(X, W1, W2, s1, s2,
                                                    N_NODES, blocks1 * 16);

    // Kernel 2: 80000 threads (8 edges each) -> 313 blocks of 256.
    const int n8 = N_EDGES / 8;
    edge_combine_kernel<<<(n8 + 255) / 256, 256, 0, stream>>>(
        ei, ei + N_EDGES, s1, s2, out, n8);
}